// Round 5
// baseline (175.588 us; speedup 1.0000x reference)
//
#include <hip/hip_runtime.h>
#include <stdint.h>

#define D_IN  256
#define D_OUT 128
#define NSEQ  4096
#define NB    16
#define SW    136                       // LDS row stride in bf16 elems (128+8: bank-spread)
#define WAVE_LDS (16 * SW)              // 2176 shorts = 4352 B per wave
#define LDS_BYTES (4 * WAVE_LDS * 2)    // 17408 B per block
#define GRID_M ((NB * NSEQ) / 64)       // 1024 blocks, 64 rows/block (16 per wave)

typedef __bf16 bf16x8 __attribute__((ext_vector_type(8)));
typedef float  f32x4  __attribute__((ext_vector_type(4)));

__device__ __forceinline__ unsigned short f2bf(float f) {
  __bf16 h = (__bf16)f;                 // RNE, may fuse to v_cvt_pk_bf16_f32
  union { __bf16 h; unsigned short u; } c; c.h = h;
  return c.u;
}
__device__ __forceinline__ float bf2f(unsigned short u) {
  union { unsigned int u; float f; } a; a.u = ((unsigned int)u) << 16;
  return a.f;
}

// Transpose+convert weights to bf16 [n][k] (k contiguous) in ws.
__global__ __launch_bounds__(256) void prep_weights(
    const float* __restrict__ Wp, const float* __restrict__ W1, const float* __restrict__ W2,
    unsigned short* __restrict__ WpT, unsigned short* __restrict__ W1T, unsigned short* __restrict__ W2T) {
  int t = blockIdx.x * 256 + threadIdx.x;
  if (t < 256 * 128) {
    int k = t >> 7, n = t & 127;
    WpT[n * 256 + k] = f2bf(Wp[t]);
  } else if (t < 256 * 128 + 128 * 128) {
    int t2 = t - 256 * 128; int k = t2 >> 7, n = t2 & 127;
    W1T[n * 128 + k] = f2bf(W1[t2]);
  } else {
    int t3 = t - 256 * 128 - 128 * 128; int k = t3 >> 7, n = t3 & 127;
    W2T[n * 128 + k] = f2bf(W2[t3]);
  }
}

// K=128 GEMM step: acc[8] (128 cols) from wave-private wbuf A-strip and
// [n][k] weight WT in L2, B double-buffered per-ks. No barriers.
__device__ __forceinline__ void gemm128(const unsigned short* __restrict__ WT,
                                        const unsigned short* wbuf,
                                        int l16, int q, f32x4* acc) {
  bf16x8 bb[2][8];
#pragma unroll
  for (int ct = 0; ct < 8; ++ct) {
    acc[ct] = (f32x4){0.f, 0.f, 0.f, 0.f};
    bb[0][ct] = *(const bf16x8*)(WT + (size_t)(ct * 16 + l16) * 128 + q * 8);
  }
#pragma unroll
  for (int ks = 0; ks < 4; ++ks) {
    if (ks < 3) {
#pragma unroll
      for (int ct = 0; ct < 8; ++ct)
        bb[(ks + 1) & 1][ct] = *(const bf16x8*)(WT + (size_t)(ct * 16 + l16) * 128 + (ks + 1) * 32 + q * 8);
    }
    bf16x8 a = *(const bf16x8*)(wbuf + l16 * SW + ks * 32 + q * 8);
#pragma unroll
    for (int ct = 0; ct < 8; ++ct)
      acc[ct] = __builtin_amdgcn_mfma_f32_16x16x32_bf16(a, bb[ks & 1][ct], acc[ct], 0, 0, 0);
  }
}

// Wave-autonomous fused kernel: each wave owns 16 rows and a private LDS
// strip (16 x SW bf16). Zero __syncthreads. C-layout (col=lane&15,
// row=quad*4+reg) -> row-major LDS -> A-layout (A[m=lane&15][k=quad*8+j]).
template <bool USE_WS>
__global__ __launch_bounds__(256, 3) void fused3(
    const float* __restrict__ X,
    const unsigned short* __restrict__ WpT,
    const unsigned short* __restrict__ W1T,
    const unsigned short* __restrict__ W2T,
    const float* __restrict__ bproj, const float* __restrict__ b1v, const float* __restrict__ b2v,
    unsigned short* __restrict__ Y3, float* __restrict__ out, float* __restrict__ P) {
  extern __shared__ unsigned short smem[];
  const int tid  = threadIdx.x;
  const int lane = tid & 63;
  const int w    = tid >> 6;
  const int q    = lane >> 4;
  const int l16  = lane & 15;
  unsigned short* wbuf = smem + w * WAVE_LDS;       // wave-private
  const int rowbase = blockIdx.x * 64 + w * 16;     // this wave's 16 rows
  const int gw = blockIdx.x * 4 + w;                // global wave id (P row)

  f32x4 acc[8];
#pragma unroll
  for (int ct = 0; ct < 8; ++ct) acc[ct] = (f32x4){0.f, 0.f, 0.f, 0.f};

  // ---------------- GEMM1: Y1 = X @ Wp, K=256 in two 128-chunks ----------------
  for (int c = 0; c < 2; ++c) {
    // stage 16x128 fp32 -> bf16 into wbuf (coalesced 1KB/instr global reads)
#pragma unroll
    for (int t = 0; t < 8; ++t) {
      int flat4 = t * 64 + lane;
      int r = flat4 >> 5, c4 = (flat4 & 31) << 2;
      const float4 v = *(const float4*)(X + (size_t)(rowbase + r) * D_IN + c * 128 + c4);
      ushort4 u; u.x = f2bf(v.x); u.y = f2bf(v.y); u.z = f2bf(v.z); u.w = f2bf(v.w);
      *(ushort4*)(wbuf + r * SW + c4) = u;
    }
    bf16x8 bb[2][8];
#pragma unroll
    for (int ct = 0; ct < 8; ++ct)
      bb[0][ct] = *(const bf16x8*)(WpT + (size_t)(ct * 16 + l16) * 256 + c * 128 + q * 8);
#pragma unroll
    for (int ks = 0; ks < 4; ++ks) {
      if (ks < 3) {
#pragma unroll
        for (int ct = 0; ct < 8; ++ct)
          bb[(ks + 1) & 1][ct] = *(const bf16x8*)(WpT + (size_t)(ct * 16 + l16) * 256 + c * 128 + (ks + 1) * 32 + q * 8);
      }
      bf16x8 a = *(const bf16x8*)(wbuf + l16 * SW + ks * 32 + q * 8);
#pragma unroll
      for (int ct = 0; ct < 8; ++ct)
        acc[ct] = __builtin_amdgcn_mfma_f32_16x16x32_bf16(a, bb[ks & 1][ct], acc[ct], 0, 0, 0);
    }
  }

  // ---- epilogue1: Y1 = acc + bproj -> wbuf (row-major bf16) ----
#pragma unroll
  for (int ct = 0; ct < 8; ++ct) {
    const int col = ct * 16 + l16;
    const float bp = bproj[col];
#pragma unroll
    for (int r = 0; r < 4; ++r)
      wbuf[(q * 4 + r) * SW + col] = f2bf(acc[ct][r] + bp);
  }

  // ---- GEMM2 + relu(+b1) -> wbuf ----
  gemm128(W1T, wbuf, l16, q, acc);
#pragma unroll
  for (int ct = 0; ct < 8; ++ct) {
    const int col = ct * 16 + l16;
    const float bb1 = b1v[col];
#pragma unroll
    for (int r = 0; r < 4; ++r) {
      float v = acc[ct][r] + bb1;
      v = v > 0.f ? v : 0.f;
      wbuf[(q * 4 + r) * SW + col] = f2bf(v);
    }
  }

  // ---- GEMM3 ----
  gemm128(W2T, wbuf, l16, q, acc);

  // ---- epilogue3: Y3 = acc + b2 -> wbuf bf16; wave col sums -> P[gw] ----
#pragma unroll
  for (int ct = 0; ct < 8; ++ct) {
    const int col = ct * 16 + l16;
    const float bb2 = b2v[col];
    float s = 0.f;
#pragma unroll
    for (int r = 0; r < 4; ++r) {
      float v = acc[ct][r] + bb2;
      s += v;
      wbuf[(q * 4 + r) * SW + col] = f2bf(v);
    }
    s += __shfl_down(s, 16);
    s += __shfl_down(s, 32);
    if (lane < 16) P[(size_t)gw * 128 + col] = s;
  }

  // ---- copy-out (wave-local LDS read, coalesced global store) ----
  if (USE_WS) {
#pragma unroll
    for (int it = 0; it < 4; ++it) {
      int i = it * 64 + lane;             // 16 rows x 16 granules of 8 bf16
      int r = i >> 4, g = i & 15;
      *(uint4*)(Y3 + (size_t)(rowbase + r) * 128 + g * 8) =
          *(const uint4*)(wbuf + r * SW + g * 8);
    }
  } else {
#pragma unroll
    for (int it = 0; it < 8; ++it) {
      int flat4 = it * 64 + lane;
      int r = flat4 >> 5, c4 = (flat4 & 31) << 2;
      ushort4 u = *(const ushort4*)(wbuf + r * SW + c4);
      float4 v; v.x = bf2f(u.x); v.y = bf2f(u.y); v.z = bf2f(u.z); v.w = bf2f(u.w);
      *(float4*)(out + (size_t)(rowbase + r) * D_OUT + c4) = v;
    }
  }
}

// S[b][col] = sum over the 256 wave-partials of batch b. grid (16,4), 256 thr.
__global__ __launch_bounds__(256) void reduce_S(const float* __restrict__ P, float* __restrict__ S) {
  __shared__ float red[256];
  int b = blockIdx.x;
  int col = blockIdx.y * 32 + (threadIdx.x & 31);
  int seg = threadIdx.x >> 5;
  float s = 0.f;
#pragma unroll
  for (int i = 0; i < 32; ++i) s += P[(size_t)(b * 256 + seg * 32 + i) * 128 + col];
  red[threadIdx.x] = s;
  __syncthreads();
  if (seg == 0) {
    float t = s;
#pragma unroll
    for (int k = 1; k < 8; ++k) t += red[k * 32 + (threadIdx.x & 31)];
    S[b * 128 + col] = t;
  }
}

// out[row][d] = S[b][d] - Y3_bf16[row][d]; 8 elems/thread
__global__ __launch_bounds__(256) void finalize_ws(
    float* __restrict__ out, const unsigned short* __restrict__ Y3, const float* __restrict__ S) {
  size_t g = (size_t)blockIdx.x * 256 + threadIdx.x;
  size_t base = g * 8;
  int row = (int)(base >> 7);
  int col = (int)(base & 127);
  int b = row >> 12;
  uint4 u = *(const uint4*)(Y3 + base);
  float4 s0 = *(const float4*)(S + (b << 7) + col);
  float4 s1 = *(const float4*)(S + (b << 7) + col + 4);
  union { unsigned int uu; float f; } t;
  float4 o0, o1;
  t.uu = u.x << 16;          o0.x = s0.x - t.f;
  t.uu = u.x & 0xFFFF0000u;  o0.y = s0.y - t.f;
  t.uu = u.y << 16;          o0.z = s0.z - t.f;
  t.uu = u.y & 0xFFFF0000u;  o0.w = s0.w - t.f;
  t.uu = u.z << 16;          o1.x = s1.x - t.f;
  t.uu = u.z & 0xFFFF0000u;  o1.y = s1.y - t.f;
  t.uu = u.w << 16;          o1.z = s1.z - t.f;
  t.uu = u.w & 0xFFFF0000u;  o1.w = s1.w - t.f;
  *(float4*)(out + base) = o0;
  *(float4*)(out + base + 4) = o1;
}

// fallback: out[row][d] = S[b][d] - out[row][d], in place
__global__ __launch_bounds__(256) void finalize_ip(float* __restrict__ out, const float* __restrict__ S) {
  size_t g = (size_t)blockIdx.x * 256 + threadIdx.x;
  size_t base = g * 8;
  int row = (int)(base >> 7);
  int col = (int)(base & 127);
  int b = row >> 12;
  float4 s0 = *(const float4*)(S + (b << 7) + col);
  float4 s1 = *(const float4*)(S + (b << 7) + col + 4);
  float4 y0 = *(const float4*)(out + base);
  float4 y1 = *(const float4*)(out + base + 4);
  float4 o0, o1;
  o0.x = s0.x - y0.x; o0.y = s0.y - y0.y; o0.z = s0.z - y0.z; o0.w = s0.w - y0.w;
  o1.x = s1.x - y1.x; o1.y = s1.y - y1.y; o1.z = s1.z - y1.z; o1.w = s1.w - y1.w;
  *(float4*)(out + base) = o0;
  *(float4*)(out + base + 4) = o1;
}

extern "C" void kernel_launch(void* const* d_in, const int* in_sizes, int n_in,
                              void* d_out, int out_size, void* d_ws, size_t ws_size,
                              hipStream_t stream) {
  const float* X  = (const float*)d_in[0];
  const float* Wp = (const float*)d_in[1];
  const float* bp = (const float*)d_in[2];
  const float* W1 = (const float*)d_in[3];
  const float* b1 = (const float*)d_in[4];
  const float* W2 = (const float*)d_in[5];
  const float* b2 = (const float*)d_in[6];
  float* out = (float*)d_out;

  char* ws = (char*)d_ws;
  float* S = (float*)ws;                                          // 8 KB
  unsigned short* WpT = (unsigned short*)(ws + 8192);             // 64 KB
  unsigned short* W1T = (unsigned short*)(ws + 8192 + 65536);     // 32 KB
  unsigned short* W2T = (unsigned short*)(ws + 8192 + 65536 + 32768);
  float* P = (float*)(ws + 8192 + 131072);                        // 2 MB (4096 x 128)
  unsigned short* Y3 = (unsigned short*)(ws + 8192 + 131072 + 2097152);  // 16 MB

  const size_t need = 8192 + 131072 + 2097152 + (size_t)NB * NSEQ * D_OUT * 2;
  const bool use_ws = ws_size >= need;

  prep_weights<<<256, 256, 0, stream>>>(Wp, W1, W2, WpT, W1T, W2T);

  const int fin_blocks = (NB * NSEQ * D_OUT) / (8 * 256);  // 4096
  if (use_ws) {
    fused3<true><<<GRID_M, 256, LDS_BYTES, stream>>>(X, WpT, W1T, W2T, bp, b1, b2, Y3, out, P);
    reduce_S<<<dim3(NB, 4), 256, 0, stream>>>(P, S);
    finalize_ws<<<fin_blocks, 256, 0, stream>>>(out, Y3, S);
  } else {
    fused3<false><<<GRID_M, 256, LDS_BYTES, stream>>>(X, WpT, W1T, W2T, bp, b1, b2, Y3, out, P);
    reduce_S<<<dim3(NB, 4), 256, 0, stream>>>(P, S);
    finalize_ip<<<fin_blocks, 256, 0, stream>>>(out, S);
  }
}

// Round 6
// 137.173 us; speedup vs baseline: 1.2801x; 1.2801x over previous
//
#include <hip/hip_runtime.h>
#include <stdint.h>

#define D_IN  256
#define D_OUT 128
#define NSEQ  4096
#define NB    16
#define TILE_M 64
#define GRID_M ((NB * NSEQ) / TILE_M)   // 1024 blocks
#define LDS_BYTES 32768                 // bufA + bufB, 16 KB each

typedef __bf16 bf16x8 __attribute__((ext_vector_type(8)));
typedef float  f32x4  __attribute__((ext_vector_type(4)));

__device__ __forceinline__ unsigned short f2bf(float f) {
  __bf16 h = (__bf16)f;
  union { __bf16 h; unsigned short u; } c; c.h = h;
  return c.u;
}
__device__ __forceinline__ float bf2f(unsigned short u) {
  union { unsigned int u; float f; } a; a.u = ((unsigned int)u) << 16;
  return a.f;
}

// Transpose+convert weights to bf16 [n][k] (k contiguous) in ws.
__global__ __launch_bounds__(256) void prep_weights(
    const float* __restrict__ Wp, const float* __restrict__ W1, const float* __restrict__ W2,
    unsigned short* __restrict__ WpT, unsigned short* __restrict__ W1T, unsigned short* __restrict__ W2T) {
  int t = blockIdx.x * 256 + threadIdx.x;
  if (t < 256 * 128) {
    int k = t >> 7, n = t & 127;
    WpT[n * 256 + k] = f2bf(Wp[t]);
  } else if (t < 256 * 128 + 128 * 128) {
    int t2 = t - 256 * 128; int k = t2 >> 7, n = t2 & 127;
    W1T[n * 128 + k] = f2bf(W1[t2]);
  } else {
    int t3 = t - 256 * 128 - 128 * 128; int k = t3 >> 7, n = t3 & 127;
    W2T[n * 128 + k] = f2bf(W2[t3]);
  }
}

// Weights REGISTER-RESIDENT per wave (32 bf16x8 = 128 VGPRs, loaded once,
// fenced against sinking). A-tiles double-buffered in swizzled LDS.
// Wave w: cols [w*32, w*32+32) (2 ct), all 64 rows (4 rt).
// LDS swizzle: (row,col) -> row*128 + ((col>>3 ^ (row&15))<<3) + (col&7).
template <bool USE_WS>
__global__ __launch_bounds__(256, 2) void fused3(
    const float* __restrict__ X,
    const unsigned short* __restrict__ WpT,
    const unsigned short* __restrict__ W1T,
    const unsigned short* __restrict__ W2T,
    const float* __restrict__ bproj, const float* __restrict__ b1v, const float* __restrict__ b2v,
    unsigned short* __restrict__ Y3, float* __restrict__ out, float* __restrict__ P) {
  extern __shared__ unsigned short smem[];
  unsigned short* bufA = smem;            // 64x128 bf16 swizzled
  unsigned short* bufB = smem + 8192;

  const int tid  = threadIdx.x;
  const int lane = tid & 63;
  const int w    = tid >> 6;
  const int q    = lane >> 4;
  const int l16  = lane & 15;
  const int rowbase = blockIdx.x * TILE_M;
  const int col0 = w * 32 + l16;
  const int col1 = col0 + 16;

  // ---- load ALL weight fragments for this wave's 32 cols; keep resident ----
  bf16x8 wp0[2][4], wp1[2][4], w1f[2][4], w2f[2][4];   // [ct][ks]
#pragma unroll
  for (int ks = 0; ks < 4; ++ks) {
    wp0[0][ks] = *(const bf16x8*)(WpT + (size_t)col0 * 256 + ks * 32 + q * 8);
    wp0[1][ks] = *(const bf16x8*)(WpT + (size_t)col1 * 256 + ks * 32 + q * 8);
    wp1[0][ks] = *(const bf16x8*)(WpT + (size_t)col0 * 256 + 128 + ks * 32 + q * 8);
    wp1[1][ks] = *(const bf16x8*)(WpT + (size_t)col1 * 256 + 128 + ks * 32 + q * 8);
    w1f[0][ks] = *(const bf16x8*)(W1T + (size_t)col0 * 128 + ks * 32 + q * 8);
    w1f[1][ks] = *(const bf16x8*)(W1T + (size_t)col1 * 128 + ks * 32 + q * 8);
    w2f[0][ks] = *(const bf16x8*)(W2T + (size_t)col0 * 128 + ks * 32 + q * 8);
    w2f[1][ks] = *(const bf16x8*)(W2T + (size_t)col1 * 128 + ks * 32 + q * 8);
  }
  __builtin_amdgcn_sched_barrier(0);   // do NOT sink these loads

  // ---- stage X chunk0 -> bufA ----
#pragma unroll
  for (int it = 0; it < 8; ++it) {
    int i = tid + it * 256;
    int r = i >> 5, c4 = (i & 31) << 2;
    const float4 v = *(const float4*)(X + (size_t)(rowbase + r) * D_IN + c4);
    ushort4 u; u.x = f2bf(v.x); u.y = f2bf(v.y); u.z = f2bf(v.z); u.w = f2bf(v.w);
    *(ushort4*)(bufA + r * 128 + ((((c4 >> 3) ^ (r & 15)) << 3) + (c4 & 7))) = u;
  }

  f32x4 acc[4][2];
#pragma unroll
  for (int rt = 0; rt < 4; ++rt) {
    acc[rt][0] = (f32x4){0.f, 0.f, 0.f, 0.f};
    acc[rt][1] = (f32x4){0.f, 0.f, 0.f, 0.f};
  }
  __syncthreads();   // #1: bufA ready

  // ---- prefetch X chunk1 (in flight during GEMM1-c0) ----
  float4 xv[8];
#pragma unroll
  for (int it = 0; it < 8; ++it) {
    int i = tid + it * 256;
    int r = i >> 5, c4 = (i & 31) << 2;
    xv[it] = *(const float4*)(X + (size_t)(rowbase + r) * D_IN + 128 + c4);
  }

  // ---- GEMM1 chunk0 (bufA, wp0) ----
#pragma unroll
  for (int ks = 0; ks < 4; ++ks)
#pragma unroll
    for (int rt = 0; rt < 4; ++rt) {
      bf16x8 a = *(const bf16x8*)(bufA + (rt * 16 + l16) * 128 + (((4 * ks + q) ^ l16) << 3));
      acc[rt][0] = __builtin_amdgcn_mfma_f32_16x16x32_bf16(a, wp0[0][ks], acc[rt][0], 0, 0, 0);
      acc[rt][1] = __builtin_amdgcn_mfma_f32_16x16x32_bf16(a, wp0[1][ks], acc[rt][1], 0, 0, 0);
    }

  // ---- stage X chunk1 -> bufB ----
#pragma unroll
  for (int it = 0; it < 8; ++it) {
    int i = tid + it * 256;
    int r = i >> 5, c4 = (i & 31) << 2;
    ushort4 u; u.x = f2bf(xv[it].x); u.y = f2bf(xv[it].y); u.z = f2bf(xv[it].z); u.w = f2bf(xv[it].w);
    *(ushort4*)(bufB + r * 128 + ((((c4 >> 3) ^ (r & 15)) << 3) + (c4 & 7))) = u;
  }
  __syncthreads();   // #2: bufB ready; all waves past GEMM1-c0 (bufA free)

  // ---- GEMM1 chunk1 (bufB, wp1) ----
#pragma unroll
  for (int ks = 0; ks < 4; ++ks)
#pragma unroll
    for (int rt = 0; rt < 4; ++rt) {
      bf16x8 a = *(const bf16x8*)(bufB + (rt * 16 + l16) * 128 + (((4 * ks + q) ^ l16) << 3));
      acc[rt][0] = __builtin_amdgcn_mfma_f32_16x16x32_bf16(a, wp1[0][ks], acc[rt][0], 0, 0, 0);
      acc[rt][1] = __builtin_amdgcn_mfma_f32_16x16x32_bf16(a, wp1[1][ks], acc[rt][1], 0, 0, 0);
    }

  // ---- epilogue1: Y1 = acc + bproj -> bufA ----
  {
    const float bp0 = bproj[col0], bp1 = bproj[col1];
#pragma unroll
    for (int rt = 0; rt < 4; ++rt)
#pragma unroll
      for (int r = 0; r < 4; ++r) {
        int row = rt * 16 + q * 4 + r;
        int sw = (row & 15) << 3;
        bufA[row * 128 + ((((col0 >> 3) << 3) ^ sw) + (col0 & 7))] = f2bf(acc[rt][0][r] + bp0);
        bufA[row * 128 + ((((col1 >> 3) << 3) ^ sw) + (col1 & 7))] = f2bf(acc[rt][1][r] + bp1);
      }
  }
  __syncthreads();   // #3: Y1 visible; all waves past GEMM1-c1 (bufB free)

  // ---- GEMM2 (bufA, w1f) ----
#pragma unroll
  for (int rt = 0; rt < 4; ++rt) {
    acc[rt][0] = (f32x4){0.f, 0.f, 0.f, 0.f};
    acc[rt][1] = (f32x4){0.f, 0.f, 0.f, 0.f};
  }
#pragma unroll
  for (int ks = 0; ks < 4; ++ks)
#pragma unroll
    for (int rt = 0; rt < 4; ++rt) {
      bf16x8 a = *(const bf16x8*)(bufA + (rt * 16 + l16) * 128 + (((4 * ks + q) ^ l16) << 3));
      acc[rt][0] = __builtin_amdgcn_mfma_f32_16x16x32_bf16(a, w1f[0][ks], acc[rt][0], 0, 0, 0);
      acc[rt][1] = __builtin_amdgcn_mfma_f32_16x16x32_bf16(a, w1f[1][ks], acc[rt][1], 0, 0, 0);
    }

  // ---- epilogue2: Y2 = relu(acc + b1) -> bufB ----
  {
    const float bb0 = b1v[col0], bb1 = b1v[col1];
#pragma unroll
    for (int rt = 0; rt < 4; ++rt)
#pragma unroll
      for (int r = 0; r < 4; ++r) {
        int row = rt * 16 + q * 4 + r;
        int sw = (row & 15) << 3;
        float v0 = acc[rt][0][r] + bb0; v0 = v0 > 0.f ? v0 : 0.f;
        float v1 = acc[rt][1][r] + bb1; v1 = v1 > 0.f ? v1 : 0.f;
        bufB[row * 128 + ((((col0 >> 3) << 3) ^ sw) + (col0 & 7))] = f2bf(v0);
        bufB[row * 128 + ((((col1 >> 3) << 3) ^ sw) + (col1 & 7))] = f2bf(v1);
      }
  }
  __syncthreads();   // #4: Y2 visible; all waves past GEMM2 (bufA free)

  // ---- GEMM3 (bufB, w2f) ----
#pragma unroll
  for (int rt = 0; rt < 4; ++rt) {
    acc[rt][0] = (f32x4){0.f, 0.f, 0.f, 0.f};
    acc[rt][1] = (f32x4){0.f, 0.f, 0.f, 0.f};
  }
#pragma unroll
  for (int ks = 0; ks < 4; ++ks)
#pragma unroll
    for (int rt = 0; rt < 4; ++rt) {
      bf16x8 a = *(const bf16x8*)(bufB + (rt * 16 + l16) * 128 + (((4 * ks + q) ^ l16) << 3));
      acc[rt][0] = __builtin_amdgcn_mfma_f32_16x16x32_bf16(a, w2f[0][ks], acc[rt][0], 0, 0, 0);
      acc[rt][1] = __builtin_amdgcn_mfma_f32_16x16x32_bf16(a, w2f[1][ks], acc[rt][1], 0, 0, 0);
    }

  // ---- epilogue3: Y3 = acc + b2 -> bufA; wave col sums -> P[block] ----
  {
    const float bb0 = b2v[col0], bb1 = b2v[col1];
    float s0 = 0.f, s1 = 0.f;
#pragma unroll
    for (int rt = 0; rt < 4; ++rt)
#pragma unroll
      for (int r = 0; r < 4; ++r) {
        int row = rt * 16 + q * 4 + r;
        int sw = (row & 15) << 3;
        float v0 = acc[rt][0][r] + bb0;
        float v1 = acc[rt][1][r] + bb1;
        s0 += v0; s1 += v1;
        bufA[row * 128 + ((((col0 >> 3) << 3) ^ sw) + (col0 & 7))] = f2bf(v0);
        bufA[row * 128 + ((((col1 >> 3) << 3) ^ sw) + (col1 & 7))] = f2bf(v1);
      }
    s0 += __shfl_down(s0, 16); s0 += __shfl_down(s0, 32);
    s1 += __shfl_down(s1, 16); s1 += __shfl_down(s1, 32);
    if (lane < 16) {
      P[(size_t)blockIdx.x * 128 + col0] = s0;
      P[(size_t)blockIdx.x * 128 + col1] = s1;
    }
  }
  __syncthreads();   // #5: Y3 in bufA complete

  // ---- copy-out ----
  if (USE_WS) {
#pragma unroll
    for (int it = 0; it < 4; ++it) {
      int i = tid + it * 256;
      int r = i >> 4, g = i & 15;
      *(uint4*)(Y3 + (size_t)(rowbase + r) * 128 + g * 8) =
          *(const uint4*)(bufA + r * 128 + ((g ^ (r & 15)) << 3));
    }
  } else {
#pragma unroll
    for (int it = 0; it < 8; ++it) {
      int i = tid + it * 256;
      int r = i >> 5, c4 = (i & 31) << 2;
      ushort4 u = *(const ushort4*)(bufA + r * 128 + ((((c4 >> 3) ^ (r & 15)) << 3) + (c4 & 7)));
      float4 v; v.x = bf2f(u.x); v.y = bf2f(u.y); v.z = bf2f(u.z); v.w = bf2f(u.w);
      *(float4*)(out + (size_t)(rowbase + r) * D_OUT + c4) = v;
    }
  }
}

// S[b][col] = sum of P over the 64 blocks of batch b. 16 blocks x 256 thr.
__global__ __launch_bounds__(256) void reduce_S(const float* __restrict__ P, float* __restrict__ S) {
  __shared__ float tmp[128];
  int b = blockIdx.x;
  int col = threadIdx.x & 127;
  int h = threadIdx.x >> 7;
  float s = 0.f;
#pragma unroll
  for (int i = 0; i < 32; ++i) s += P[(size_t)(b * 64 + h * 32 + i) * 128 + col];
  if (h == 1) tmp[col] = s;
  __syncthreads();
  if (h == 0) S[b * 128 + col] = s + tmp[col];
}

// out[row][d] = S[b][d] - Y3_bf16[row][d]; 8 elems/thread
__global__ __launch_bounds__(256) void finalize_ws(
    float* __restrict__ out, const unsigned short* __restrict__ Y3, const float* __restrict__ S) {
  size_t g = (size_t)blockIdx.x * 256 + threadIdx.x;
  size_t base = g * 8;
  int row = (int)(base >> 7);
  int col = (int)(base & 127);
  int b = row >> 12;
  uint4 u = *(const uint4*)(Y3 + base);
  float4 s0 = *(const float4*)(S + (b << 7) + col);
  float4 s1 = *(const float4*)(S + (b << 7) + col + 4);
  union { unsigned int uu; float f; } t;
  float4 o0, o1;
  t.uu = u.x << 16;          o0.x = s0.x - t.f;
  t.uu = u.x & 0xFFFF0000u;  o0.y = s0.y - t.f;
  t.uu = u.y << 16;          o0.z = s0.z - t.f;
  t.uu = u.y & 0xFFFF0000u;  o0.w = s0.w - t.f;
  t.uu = u.z << 16;          o1.x = s1.x - t.f;
  t.uu = u.z & 0xFFFF0000u;  o1.y = s1.y - t.f;
  t.uu = u.w << 16;          o1.z = s1.z - t.f;
  t.uu = u.w & 0xFFFF0000u;  o1.w = s1.w - t.f;
  *(float4*)(out + base) = o0;
  *(float4*)(out + base + 4) = o1;
}

// fallback: out[row][d] = S[b][d] - out[row][d], in place
__global__ __launch_bounds__(256) void finalize_ip(float* __restrict__ out, const float* __restrict__ S) {
  size_t g = (size_t)blockIdx.x * 256 + threadIdx.x;
  size_t base = g * 8;
  int row = (int)(base >> 7);
  int col = (int)(base & 127);
  int b = row >> 12;
  float4 s0 = *(const float4*)(S + (b << 7) + col);
  float4 s1 = *(const float4*)(S + (b << 7) + col + 4);
  float4 y0 = *(const float4*)(out + base);
  float4 y1 = *(const float4*)(out + base + 4);
  float4 o0, o1;
  o0.x = s0.x - y0.x; o0.y = s0.y - y0.y; o0.z = s0.z - y0.z; o0.w = s0.w - y0.w;
  o1.x = s1.x - y1.x; o1.y = s1.y - y1.y; o1.z = s1.z - y1.z; o1.w = s1.w - y1.w;
  *(float4*)(out + base) = o0;
  *(float4*)(out + base + 4) = o1;
}

extern "C" void kernel_launch(void* const* d_in, const int* in_sizes, int n_in,
                              void* d_out, int out_size, void* d_ws, size_t ws_size,
                              hipStream_t stream) {
  const float* X  = (const float*)d_in[0];
  const float* Wp = (const float*)d_in[1];
  const float* bp = (const float*)d_in[2];
  const float* W1 = (const float*)d_in[3];
  const float* b1 = (const float*)d_in[4];
  const float* W2 = (const float*)d_in[5];
  const float* b2 = (const float*)d_in[6];
  float* out = (float*)d_out;

  char* ws = (char*)d_ws;
  float* S = (float*)ws;                                          // 8 KB
  unsigned short* WpT = (unsigned short*)(ws + 8192);             // 64 KB
  unsigned short* W1T = (unsigned short*)(ws + 8192 + 65536);     // 32 KB
  unsigned short* W2T = (unsigned short*)(ws + 8192 + 65536 + 32768);
  float* P = (float*)(ws + 8192 + 131072);                        // 512 KB (1024 x 128)
  unsigned short* Y3 = (unsigned short*)(ws + 8192 + 131072 + 524288);  // 16 MB

  const size_t need = 8192 + 131072 + 524288 + (size_t)NB * NSEQ * D_OUT * 2;
  const bool use_ws = ws_size >= need;

  prep_weights<<<256, 256, 0, stream>>>(Wp, W1, W2, WpT, W1T, W2T);

  const int fin_blocks = (NB * NSEQ * D_OUT) / (8 * 256);  // 4096
  if (use_ws) {
    fused3<true><<<GRID_M, 256, LDS_BYTES, stream>>>(X, WpT, W1T, W2T, bp, b1, b2, Y3, out, P);
    reduce_S<<<NB, 256, 0, stream>>>(P, S);
    finalize_ws<<<fin_blocks, 256, 0, stream>>>(out, Y3, S);
  } else {
    fused3<false><<<GRID_M, 256, LDS_BYTES, stream>>>(X, WpT, W1T, W2T, bp, b1, b2, Y3, out, P);
    reduce_S<<<NB, 256, 0, stream>>>(P, S);
    finalize_ip<<<fin_blocks, 256, 0, stream>>>(out, S);
  }
}

// Round 7
// 134.028 us; speedup vs baseline: 1.3101x; 1.0235x over previous
//
#include <hip/hip_runtime.h>
#include <stdint.h>

#define D_IN  256
#define D_OUT 128
#define NSEQ  4096
#define NB    16
#define TILE_M 64
#define GRID_M ((NB * NSEQ) / TILE_M)   // 1024 blocks
#define LDS_BYTES 32768                 // bufA + bufB, 16 KB each

typedef __bf16 bf16x8 __attribute__((ext_vector_type(8)));
typedef float  f32x4  __attribute__((ext_vector_type(4)));

__device__ __forceinline__ unsigned short f2bf(float f) {
  __bf16 h = (__bf16)f;
  union { __bf16 h; unsigned short u; } c; c.h = h;
  return c.u;
}
__device__ __forceinline__ float bf2f(unsigned short u) {
  union { unsigned int u; float f; } a; a.u = ((unsigned int)u) << 16;
  return a.f;
}

// prep: Wa = Wp @ W1 (fp32 accum -> bf16, [n][k] layout), W2 transpose,
// be1 = bp @ W1 + b1. Folding Wp@W1 is exact math (ReLU is the only
// nonlinearity): relu((X@Wp+bp)@W1+b1) = relu(X@Wa + be1).
__global__ __launch_bounds__(256) void prep(
    const float* __restrict__ Wp, const float* __restrict__ W1, const float* __restrict__ W2,
    const float* __restrict__ bp, const float* __restrict__ b1,
    unsigned short* __restrict__ WaT, unsigned short* __restrict__ W2T, float* __restrict__ be1) {
  int b = blockIdx.x;
  if (b < 128) {
    // rows k0, k0+1 of Wa
    __shared__ float wp[256];
    int k0 = b * 2;
    wp[threadIdx.x] = Wp[k0 * 128 + threadIdx.x];
    __syncthreads();
    int kk = threadIdx.x >> 7, n = threadIdx.x & 127;
    float s = 0.f;
#pragma unroll 16
    for (int j = 0; j < 128; ++j) s += wp[kk * 128 + j] * W1[j * 128 + n];
    WaT[n * 256 + (k0 + kk)] = f2bf(s);
  } else if (b < 192) {
    int t = (b - 128) * 256 + threadIdx.x;
    int k = t >> 7, n = t & 127;
    W2T[n * 128 + k] = f2bf(W2[t]);
  } else {
    if (threadIdx.x < 128) {
      int n = threadIdx.x;
      float s = b1[n];
#pragma unroll 16
      for (int j = 0; j < 128; ++j) s += bp[j] * W1[j * 128 + n];
      be1[n] = s;
    }
  }
}

// 2 chained GEMMs per 64-row tile: Y2 = relu(X@Wa + be1)  (K=256, 2 chunks),
// Y3 = Y2@W2 + b2 (K=128). A tiles in swizzled LDS (bufA/bufB); B frags
// prefetched one GEMM ahead. Wave w: cols [w*32,w*32+32), all 64 rows.
// No atomics: per-block col sums -> P[block][128].
// LDS swizzle: (row,col) -> row*128 + ((col>>3 ^ (row&15))<<3) + (col&7).
template <bool USE_WS>
__global__ __launch_bounds__(256, 3) void fused2(
    const float* __restrict__ X,
    const unsigned short* __restrict__ WaT,
    const unsigned short* __restrict__ W2T,
    const float* __restrict__ be1, const float* __restrict__ b2v,
    unsigned short* __restrict__ Y3, float* __restrict__ out, float* __restrict__ P) {
  extern __shared__ unsigned short smem[];
  unsigned short* bufA = smem;            // 64x128 bf16 swizzled
  unsigned short* bufB = smem + 8192;

  const int tid  = threadIdx.x;
  const int lane = tid & 63;
  const int w    = tid >> 6;
  const int q    = lane >> 4;
  const int l16  = lane & 15;
  const int rowbase = blockIdx.x * TILE_M;
  const int col0 = w * 32 + l16;
  const int col1 = col0 + 16;

  f32x4 acc[4][2];
  bf16x8 bA[4][2], bB[4][2];              // [ks][ct]

  // ---- prefetch Wa chunk0 B-frags ----
#pragma unroll
  for (int ks = 0; ks < 4; ++ks) {
    bA[ks][0] = *(const bf16x8*)(WaT + (size_t)col0 * 256 + ks * 32 + q * 8);
    bA[ks][1] = *(const bf16x8*)(WaT + (size_t)col1 * 256 + ks * 32 + q * 8);
  }

  // ---- stage X chunk0 -> bufA ----
#pragma unroll
  for (int it = 0; it < 8; ++it) {
    int i = tid + it * 256;
    int r = i >> 5, c4 = (i & 31) << 2;
    const float4 v = *(const float4*)(X + (size_t)(rowbase + r) * D_IN + c4);
    ushort4 u; u.x = f2bf(v.x); u.y = f2bf(v.y); u.z = f2bf(v.z); u.w = f2bf(v.w);
    *(ushort4*)(bufA + r * 128 + ((((c4 >> 3) ^ (r & 15)) << 3) + (c4 & 7))) = u;
  }

#pragma unroll
  for (int rt = 0; rt < 4; ++rt) {
    acc[rt][0] = (f32x4){0.f, 0.f, 0.f, 0.f};
    acc[rt][1] = (f32x4){0.f, 0.f, 0.f, 0.f};
  }
  __syncthreads();   // #1: bufA ready

  // ---- prefetch X chunk1 + Wa chunk1 frags (fly during GEMM-A c0) ----
  float4 xv[8];
#pragma unroll
  for (int it = 0; it < 8; ++it) {
    int i = tid + it * 256;
    int r = i >> 5, c4 = (i & 31) << 2;
    xv[it] = *(const float4*)(X + (size_t)(rowbase + r) * D_IN + 128 + c4);
  }
#pragma unroll
  for (int ks = 0; ks < 4; ++ks) {
    bB[ks][0] = *(const bf16x8*)(WaT + (size_t)col0 * 256 + 128 + ks * 32 + q * 8);
    bB[ks][1] = *(const bf16x8*)(WaT + (size_t)col1 * 256 + 128 + ks * 32 + q * 8);
  }

  // ---- GEMM-A chunk0 (bufA, bA) ----
#pragma unroll
  for (int ks = 0; ks < 4; ++ks)
#pragma unroll
    for (int rt = 0; rt < 4; ++rt) {
      bf16x8 a = *(const bf16x8*)(bufA + (rt * 16 + l16) * 128 + (((4 * ks + q) ^ l16) << 3));
      acc[rt][0] = __builtin_amdgcn_mfma_f32_16x16x32_bf16(a, bA[ks][0], acc[rt][0], 0, 0, 0);
      acc[rt][1] = __builtin_amdgcn_mfma_f32_16x16x32_bf16(a, bA[ks][1], acc[rt][1], 0, 0, 0);
    }

  // ---- stage X chunk1 -> bufB ----
#pragma unroll
  for (int it = 0; it < 8; ++it) {
    int i = tid + it * 256;
    int r = i >> 5, c4 = (i & 31) << 2;
    ushort4 u; u.x = f2bf(xv[it].x); u.y = f2bf(xv[it].y); u.z = f2bf(xv[it].z); u.w = f2bf(xv[it].w);
    *(ushort4*)(bufB + r * 128 + ((((c4 >> 3) ^ (r & 15)) << 3) + (c4 & 7))) = u;
  }
  __syncthreads();   // #2: bufB ready; all waves past GEMM-A c0 (bufA free)

  // ---- prefetch W2 frags into bA slots (Wa-c0 frags dead) ----
#pragma unroll
  for (int ks = 0; ks < 4; ++ks) {
    bA[ks][0] = *(const bf16x8*)(W2T + (size_t)col0 * 128 + ks * 32 + q * 8);
    bA[ks][1] = *(const bf16x8*)(W2T + (size_t)col1 * 128 + ks * 32 + q * 8);
  }

  // ---- GEMM-A chunk1 (bufB, bB) ----
#pragma unroll
  for (int ks = 0; ks < 4; ++ks)
#pragma unroll
    for (int rt = 0; rt < 4; ++rt) {
      bf16x8 a = *(const bf16x8*)(bufB + (rt * 16 + l16) * 128 + (((4 * ks + q) ^ l16) << 3));
      acc[rt][0] = __builtin_amdgcn_mfma_f32_16x16x32_bf16(a, bB[ks][0], acc[rt][0], 0, 0, 0);
      acc[rt][1] = __builtin_amdgcn_mfma_f32_16x16x32_bf16(a, bB[ks][1], acc[rt][1], 0, 0, 0);
    }

  // ---- epilogue A: Y2 = relu(acc + be1) -> bufA ----
  {
    const float e0 = be1[col0], e1 = be1[col1];
#pragma unroll
    for (int rt = 0; rt < 4; ++rt)
#pragma unroll
      for (int r = 0; r < 4; ++r) {
        int row = rt * 16 + q * 4 + r;
        int sw = (row & 15) << 3;
        float v0 = acc[rt][0][r] + e0; v0 = v0 > 0.f ? v0 : 0.f;
        float v1 = acc[rt][1][r] + e1; v1 = v1 > 0.f ? v1 : 0.f;
        bufA[row * 128 + ((((col0 >> 3) << 3) ^ sw) + (col0 & 7))] = f2bf(v0);
        bufA[row * 128 + ((((col1 >> 3) << 3) ^ sw) + (col1 & 7))] = f2bf(v1);
      }
  }
  __syncthreads();   // #3: Y2 visible; all waves past GEMM-A c1 (bufB free)

  // ---- GEMM-B (bufA, bA=W2 frags) ----
#pragma unroll
  for (int rt = 0; rt < 4; ++rt) {
    acc[rt][0] = (f32x4){0.f, 0.f, 0.f, 0.f};
    acc[rt][1] = (f32x4){0.f, 0.f, 0.f, 0.f};
  }
#pragma unroll
  for (int ks = 0; ks < 4; ++ks)
#pragma unroll
    for (int rt = 0; rt < 4; ++rt) {
      bf16x8 a = *(const bf16x8*)(bufA + (rt * 16 + l16) * 128 + (((4 * ks + q) ^ l16) << 3));
      acc[rt][0] = __builtin_amdgcn_mfma_f32_16x16x32_bf16(a, bA[ks][0], acc[rt][0], 0, 0, 0);
      acc[rt][1] = __builtin_amdgcn_mfma_f32_16x16x32_bf16(a, bA[ks][1], acc[rt][1], 0, 0, 0);
    }

  // ---- epilogue B: Y3 = acc + b2 -> bufB; wave col sums -> P[block] ----
  {
    const float bb0 = b2v[col0], bb1 = b2v[col1];
    float s0 = 0.f, s1 = 0.f;
#pragma unroll
    for (int rt = 0; rt < 4; ++rt)
#pragma unroll
      for (int r = 0; r < 4; ++r) {
        int row = rt * 16 + q * 4 + r;
        int sw = (row & 15) << 3;
        float v0 = acc[rt][0][r] + bb0;
        float v1 = acc[rt][1][r] + bb1;
        s0 += v0; s1 += v1;
        bufB[row * 128 + ((((col0 >> 3) << 3) ^ sw) + (col0 & 7))] = f2bf(v0);
        bufB[row * 128 + ((((col1 >> 3) << 3) ^ sw) + (col1 & 7))] = f2bf(v1);
      }
    s0 += __shfl_down(s0, 16); s0 += __shfl_down(s0, 32);
    s1 += __shfl_down(s1, 16); s1 += __shfl_down(s1, 32);
    if (lane < 16) {
      P[(size_t)blockIdx.x * 128 + col0] = s0;
      P[(size_t)blockIdx.x * 128 + col1] = s1;
    }
  }
  __syncthreads();   // #4: Y3 in bufB complete

  // ---- copy-out ----
  if (USE_WS) {
#pragma unroll
    for (int it = 0; it < 4; ++it) {
      int i = tid + it * 256;
      int r = i >> 4, g = i & 15;
      *(uint4*)(Y3 + (size_t)(rowbase + r) * 128 + g * 8) =
          *(const uint4*)(bufB + r * 128 + ((g ^ (r & 15)) << 3));
    }
  } else {
#pragma unroll
    for (int it = 0; it < 8; ++it) {
      int i = tid + it * 256;
      int r = i >> 5, c4 = (i & 31) << 2;
      ushort4 u = *(const ushort4*)(bufB + r * 128 + ((((c4 >> 3) ^ (r & 15)) << 3) + (c4 & 7)));
      float4 v; v.x = bf2f(u.x); v.y = bf2f(u.y); v.z = bf2f(u.z); v.w = bf2f(u.w);
      *(float4*)(out + (size_t)(rowbase + r) * D_OUT + c4) = v;
    }
  }
}

// S[b][col] = sum of P over the 64 blocks of batch b. 16 blocks x 256 thr.
__global__ __launch_bounds__(256) void reduce_S(const float* __restrict__ P, float* __restrict__ S) {
  __shared__ float tmp[128];
  int b = blockIdx.x;
  int col = threadIdx.x & 127;
  int h = threadIdx.x >> 7;
  float s = 0.f;
#pragma unroll
  for (int i = 0; i < 32; ++i) s += P[(size_t)(b * 64 + h * 32 + i) * 128 + col];
  if (h == 1) tmp[col] = s;
  __syncthreads();
  if (h == 0) S[b * 128 + col] = s + tmp[col];
}

// out[row][d] = S[b][d] - Y3_bf16[row][d]; 8 elems/thread
__global__ __launch_bounds__(256) void finalize_ws(
    float* __restrict__ out, const unsigned short* __restrict__ Y3, const float* __restrict__ S) {
  size_t g = (size_t)blockIdx.x * 256 + threadIdx.x;
  size_t base = g * 8;
  int row = (int)(base >> 7);
  int col = (int)(base & 127);
  int b = row >> 12;
  uint4 u = *(const uint4*)(Y3 + base);
  float4 s0 = *(const float4*)(S + (b << 7) + col);
  float4 s1 = *(const float4*)(S + (b << 7) + col + 4);
  union { unsigned int uu; float f; } t;
  float4 o0, o1;
  t.uu = u.x << 16;          o0.x = s0.x - t.f;
  t.uu = u.x & 0xFFFF0000u;  o0.y = s0.y - t.f;
  t.uu = u.y << 16;          o0.z = s0.z - t.f;
  t.uu = u.y & 0xFFFF0000u;  o0.w = s0.w - t.f;
  t.uu = u.z << 16;          o1.x = s1.x - t.f;
  t.uu = u.z & 0xFFFF0000u;  o1.y = s1.y - t.f;
  t.uu = u.w << 16;          o1.z = s1.z - t.f;
  t.uu = u.w & 0xFFFF0000u;  o1.w = s1.w - t.f;
  *(float4*)(out + base) = o0;
  *(float4*)(out + base + 4) = o1;
}

// fallback: out[row][d] = S[b][d] - out[row][d], in place
__global__ __launch_bounds__(256) void finalize_ip(float* __restrict__ out, const float* __restrict__ S) {
  size_t g = (size_t)blockIdx.x * 256 + threadIdx.x;
  size_t base = g * 8;
  int row = (int)(base >> 7);
  int col = (int)(base & 127);
  int b = row >> 12;
  float4 s0 = *(const float4*)(S + (b << 7) + col);
  float4 s1 = *(const float4*)(S + (b << 7) + col + 4);
  float4 y0 = *(const float4*)(out + base);
  float4 y1 = *(const float4*)(out + base + 4);
  float4 o0, o1;
  o0.x = s0.x - y0.x; o0.y = s0.y - y0.y; o0.z = s0.z - y0.z; o0.w = s0.w - y0.w;
  o1.x = s1.x - y1.x; o1.y = s1.y - y1.y; o1.z = s1.z - y1.z; o1.w = s1.w - y1.w;
  *(float4*)(out + base) = o0;
  *(float4*)(out + base + 4) = o1;
}

extern "C" void kernel_launch(void* const* d_in, const int* in_sizes, int n_in,
                              void* d_out, int out_size, void* d_ws, size_t ws_size,
                              hipStream_t stream) {
  const float* X  = (const float*)d_in[0];
  const float* Wp = (const float*)d_in[1];
  const float* bp = (const float*)d_in[2];
  const float* W1 = (const float*)d_in[3];
  const float* b1 = (const float*)d_in[4];
  const float* W2 = (const float*)d_in[5];
  const float* b2 = (const float*)d_in[6];
  float* out = (float*)d_out;

  char* ws = (char*)d_ws;
  float* S            = (float*)ws;                               // 8 KB
  float* be1          = (float*)(ws + 8192);                      // 4 KB (512 B used)
  unsigned short* WaT = (unsigned short*)(ws + 12288);            // 64 KB (256x128 bf16 [n][k])
  unsigned short* W2T = (unsigned short*)(ws + 12288 + 65536);    // 32 KB
  float* P            = (float*)(ws + 12288 + 65536 + 32768);     // 512 KB (1024 x 128)
  unsigned short* Y3  = (unsigned short*)(ws + 12288 + 65536 + 32768 + 524288);  // 16 MB

  const size_t need = 12288 + 65536 + 32768 + 524288 + (size_t)NB * NSEQ * D_OUT * 2;
  const bool use_ws = ws_size >= need;

  prep<<<193, 256, 0, stream>>>(Wp, W1, W2, bp, b1, WaT, W2T, be1);

  const int fin_blocks = (NB * NSEQ * D_OUT) / (8 * 256);  // 4096
  if (use_ws) {
    fused2<true><<<GRID_M, 256, LDS_BYTES, stream>>>(X, WaT, W2T, be1, b2, Y3, out, P);
    reduce_S<<<NB, 256, 0, stream>>>(P, S);
    finalize_ws<<<fin_blocks, 256, 0, stream>>>(out, Y3, S);
  } else {
    fused2<false><<<GRID_M, 256, LDS_BYTES, stream>>>(X, WaT, W2T, be1, b2, Y3, out, P);
    reduce_S<<<NB, 256, 0, stream>>>(P, S);
    finalize_ip<<<fin_blocks, 256, 0, stream>>>(out, S);
  }
}